// Round 6
// baseline (456.261 us; speedup 1.0000x reference)
//
#include <hip/hip_runtime.h>
#include <hip/hip_bf16.h>

// Problem constants
#define B_SZ   4
#define S_LEN  2048
#define E_DIM  1024
#define H_NUM  16
#define D_DIM  64
#define M_ROWS (B_SZ * S_LEN)            // 8192
#define QK_SCALE 0.1803368801111204f     // (1/sqrt(64)) * log2(e): softmax in exp2 domain

typedef __attribute__((ext_vector_type(8))) __bf16 bf16x8;
typedef __attribute__((ext_vector_type(4))) float  f32x4;

__device__ __forceinline__ bf16x8 load8(const __hip_bfloat16* p) {
    return __builtin_bit_cast(bf16x8, *reinterpret_cast<const uint4*>(p));
}
__device__ __forceinline__ __bf16 tobf(float x) {
    return __builtin_bit_cast(__bf16, __float2bfloat16(x));
}

#if defined(__has_builtin)
#if __has_builtin(__builtin_amdgcn_exp2f)
#define EXP2F(x) __builtin_amdgcn_exp2f(x)
#endif
#if __has_builtin(__builtin_amdgcn_global_load_lds)
#define HAVE_GLL 1
#endif
#endif
#ifndef EXP2F
#define EXP2F(x) exp2f(x)
#endif

// 16B-per-lane global->LDS stage. lbase wave-uniform; lane i lands at lbase+16i.
__device__ __forceinline__ void stage16g(const void* g, void* lbase, int lane) {
#ifdef HAVE_GLL
    __builtin_amdgcn_global_load_lds((const __attribute__((address_space(1))) unsigned int*)g,
                                     (__attribute__((address_space(3))) unsigned int*)lbase,
                                     16, 0, 0);
#else
    reinterpret_cast<uint4*>(lbase)[lane] = *reinterpret_cast<const uint4*>(g);
#endif
}

// ---------------------------------------------------------------------------
// f32 -> bf16 convert (weights only now), 8 elements/thread.
// ---------------------------------------------------------------------------
__global__ __launch_bounds__(256) void cvt_f32_bf16(const float* __restrict__ s,
                                                    __hip_bfloat16* __restrict__ d,
                                                    int n8)
{
    const int i = blockIdx.x * 256 + threadIdx.x;
    if (i >= n8) return;
    const float4 a = reinterpret_cast<const float4*>(s)[i * 2];
    const float4 b = reinterpret_cast<const float4*>(s)[i * 2 + 1];
    __hip_bfloat16 o[8];
    o[0] = __float2bfloat16(a.x); o[1] = __float2bfloat16(a.y);
    o[2] = __float2bfloat16(a.z); o[3] = __float2bfloat16(a.w);
    o[4] = __float2bfloat16(b.x); o[5] = __float2bfloat16(b.y);
    o[6] = __float2bfloat16(b.z); o[7] = __float2bfloat16(b.w);
    reinterpret_cast<uint4*>(d)[i] = *reinterpret_cast<uint4*>(o);
}

// ---------------------------------------------------------------------------
// Fused QKV projection GEMM: out = A(f32) @ W(bf16)^T + bias, 128x128 tile,
// BK=32, double-buffered global_load_lds (1 barrier/iter, prefetch-before-
// compute). A staged as f32 and converted to bf16 at frag assembly.
// XOR granule swizzle (16B granules, source-permuted so the linear DMA gives
// conflict-light frag reads: A 2-way, B 4-way).
// grid = 3 * 512: blockIdx>>9 selects projection (Q/K/V).
// Epilogue: headsT=0 -> [bh][s][d]; headsT=1 -> [bh][d][s]. scale on (acc+b).
// ---------------------------------------------------------------------------
struct QkvDesc { const float* A; const __hip_bfloat16* W; const float* bias;
                 __hip_bfloat16* out; float scale; int headsT; };
struct QkvArgs { QkvDesc d[3]; };

__global__ __launch_bounds__(256) void gemm_qkv(QkvArgs args)
{
    __shared__ float          AlsF[2][128 * 32];  // 2 x 16 KB
    __shared__ __hip_bfloat16 Bls [2][128 * 32];  // 2 x  8 KB

    const int proj = blockIdx.x >> 9;
    const int bidx = blockIdx.x & 511;
    const QkvDesc g = args.d[proj];

    const int wave = threadIdx.x >> 6, lane = threadIdx.x & 63;
    const int quad = lane >> 4, l16 = lane & 15;
    const int bm = bidx >> 3, bn = bidx & 7;
    const int row0 = bm * 128, col0 = bn * 128;
    const int wm = (wave & 1) * 64, wn = (wave >> 1) * 64;

    // A staging source (f32): lane i -> row i>>3 (of 8-row seg), granule (i&7)^(row&7)
    const int arow = lane >> 3;
    const int agrn = (lane & 7) ^ (arow & 7);
    const float* gA = g.A + (size_t)(row0 + wave * 32 + arow) * E_DIM + agrn * 4;
    // B staging source (bf16): lane i -> row i>>2, granule (i&3)^(row&3)
    const int brow = lane >> 2;
    const int bgrn = (lane & 3) ^ (brow & 3);
    const __hip_bfloat16* gB = g.W + (size_t)(col0 + wave * 32 + brow) * E_DIM + bgrn * 8;

    f32x4 zero = {0.f, 0.f, 0.f, 0.f};
    f32x4 acc[4][4];
#pragma unroll
    for (int i = 0; i < 4; i++)
#pragma unroll
        for (int j = 0; j < 4; j++) acc[i][j] = zero;

    auto stage = [&](int buf, int kk) {
#pragma unroll
        for (int seg = 0; seg < 4; seg++)
            stage16g(gA + kk + (size_t)seg * 8 * E_DIM,
                     &AlsF[buf][(wave * 32 + seg * 8) * 32], lane);
#pragma unroll
        for (int seg = 0; seg < 2; seg++)
            stage16g(gB + kk + (size_t)seg * 16 * E_DIM,
                     &Bls[buf][(wave * 32 + seg * 16) * 32], lane);
    };

    stage(0, 0);
    __syncthreads();
    for (int it = 0; it < 32; ++it) {
        const int cb = it & 1;
        if (it < 31) stage(cb ^ 1, (it + 1) * 32);   // async prefetch, lands during compute

        bf16x8 a[4], b[4];
#pragma unroll
        for (int i = 0; i < 4; i++) {
            const int row = wm + i * 16 + l16;
            const float* base = &AlsF[cb][row * 32];
            const f32x4 lo = *reinterpret_cast<const f32x4*>(base + ((2 * quad)     ^ (l16 & 7)) * 4);
            const f32x4 hi = *reinterpret_cast<const f32x4*>(base + ((2 * quad + 1) ^ (l16 & 7)) * 4);
            bf16x8 av;
#pragma unroll
            for (int e = 0; e < 4; e++) { av[e] = tobf(lo[e]); av[4 + e] = tobf(hi[e]); }
            a[i] = av;
        }
#pragma unroll
        for (int j = 0; j < 4; j++) {
            const int row = wn + j * 16 + l16;
            b[j] = load8(&Bls[cb][row * 32 + ((quad ^ (l16 & 3)) * 8)]);
        }
#pragma unroll
        for (int i = 0; i < 4; i++)
#pragma unroll
            for (int j = 0; j < 4; j++)
                acc[i][j] = __builtin_amdgcn_mfma_f32_16x16x32_bf16(a[i], b[j], acc[i][j], 0, 0, 0);
        __syncthreads();   // after compute: prefetch drain overlaps compute
    }

#pragma unroll
    for (int j = 0; j < 4; j++) {
        const int col = col0 + wn + j * 16 + l16;
        const float bv = g.bias[col];
        const int h_ = col >> 6, d_ = col & 63;
#pragma unroll
        for (int i = 0; i < 4; i++) {
            const int row = row0 + wm + i * 16 + quad * 4;
#pragma unroll
            for (int r = 0; r < 4; r++) {
                const float v = (acc[i][j][r] + bv) * g.scale;
                const int rr = row + r;
                const int b_ = rr >> 11, s_ = rr & 2047;
                if (!g.headsT)
                    g.out[(((size_t)(b_ * H_NUM + h_)) << 17) + (s_ << 6) + d_] = __float2bfloat16(v);
                else
                    g.out[(((size_t)(b_ * H_NUM + h_)) << 17) + (d_ << 11) + s_] = __float2bfloat16(v);
            }
        }
    }
}

// ---------------------------------------------------------------------------
// Output projection GEMM: C(f32) = A(bf16) @ W(bf16)^T + bias. Same dbuf
// single-barrier structure, XOR-swizzled bf16 staging for both operands.
// ---------------------------------------------------------------------------
__global__ __launch_bounds__(256) void gemm_o(const __hip_bfloat16* __restrict__ A,
                                              const __hip_bfloat16* __restrict__ W,
                                              const float* __restrict__ bias,
                                              float* __restrict__ C)
{
    __shared__ __hip_bfloat16 Als[2][128 * 32];
    __shared__ __hip_bfloat16 Bls[2][128 * 32];

    const int wave = threadIdx.x >> 6, lane = threadIdx.x & 63;
    const int quad = lane >> 4, l16 = lane & 15;
    const int bm = blockIdx.x >> 3, bn = blockIdx.x & 7;
    const int row0 = bm * 128, col0 = bn * 128;
    const int wm = (wave & 1) * 64, wn = (wave >> 1) * 64;

    const int srow = lane >> 2;
    const int sgrn = (lane & 3) ^ (srow & 3);
    const __hip_bfloat16* gA = A + (size_t)(row0 + wave * 32 + srow) * E_DIM + sgrn * 8;
    const __hip_bfloat16* gB = W + (size_t)(col0 + wave * 32 + srow) * E_DIM + sgrn * 8;

    f32x4 zero = {0.f, 0.f, 0.f, 0.f};
    f32x4 acc[4][4];
#pragma unroll
    for (int i = 0; i < 4; i++)
#pragma unroll
        for (int j = 0; j < 4; j++) acc[i][j] = zero;

    auto stage = [&](int buf, int kk) {
#pragma unroll
        for (int seg = 0; seg < 2; seg++) {
            stage16g(gA + kk + (size_t)seg * 16 * E_DIM,
                     &Als[buf][(wave * 32 + seg * 16) * 32], lane);
            stage16g(gB + kk + (size_t)seg * 16 * E_DIM,
                     &Bls[buf][(wave * 32 + seg * 16) * 32], lane);
        }
    };

    stage(0, 0);
    __syncthreads();
    for (int it = 0; it < 32; ++it) {
        const int cb = it & 1;
        if (it < 31) stage(cb ^ 1, (it + 1) * 32);

        bf16x8 a[4], b[4];
#pragma unroll
        for (int i = 0; i < 4; i++)
            a[i] = load8(&Als[cb][(wm + i * 16 + l16) * 32 + ((quad ^ (l16 & 3)) * 8)]);
#pragma unroll
        for (int j = 0; j < 4; j++)
            b[j] = load8(&Bls[cb][(wn + j * 16 + l16) * 32 + ((quad ^ (l16 & 3)) * 8)]);
#pragma unroll
        for (int i = 0; i < 4; i++)
#pragma unroll
            for (int j = 0; j < 4; j++)
                acc[i][j] = __builtin_amdgcn_mfma_f32_16x16x32_bf16(a[i], b[j], acc[i][j], 0, 0, 0);
        __syncthreads();
    }

#pragma unroll
    for (int j = 0; j < 4; j++) {
        const int col = col0 + wn + j * 16 + l16;
        const float bv = bias[col];
#pragma unroll
        for (int i = 0; i < 4; i++) {
            const int row = row0 + wm + i * 16 + quad * 4;
#pragma unroll
            for (int r = 0; r < 4; r++)
                C[(size_t)(row + r) * E_DIM + col] = acc[i][j][r] + bv;
        }
    }
}

// ---------------------------------------------------------------------------
// Flash attention v3: barrier-free, 64 q-rows/wave, S^T trick, no-max exp2
// softmax, register-double-buffered K prefetch, early V issue, l via ones-MFMA.
// Qt,Kt: [bh][s][d] bf16 (Qt prescaled). Vt: [bh][d][s] bf16.
// ---------------------------------------------------------------------------
__global__ __launch_bounds__(256, 2) void attn(const __hip_bfloat16* __restrict__ Qt,
                                               const __hip_bfloat16* __restrict__ Kt,
                                               const __hip_bfloat16* __restrict__ Vt,
                                               __hip_bfloat16* __restrict__ Op)
{
    __shared__ __hip_bfloat16 Pls[4][64][40];   // per-wave [qrow][key32 + pad], 20 KB

    const int qchunk = blockIdx.x & 7;
    const int bh     = blockIdx.x >> 3;
    const int wave = threadIdx.x >> 6, lane = threadIdx.x & 63;
    const int quad = lane >> 4, l16 = lane & 15;
    const int qrow0 = qchunk * 256 + wave * 64;

    const __hip_bfloat16* qb = Qt + ((size_t)bh << 17);
    const __hip_bfloat16* kb = Kt + ((size_t)bh << 17);
    const __hip_bfloat16* vb = Vt + ((size_t)bh << 17);
    __hip_bfloat16* pw = &Pls[wave][0][0];

    bf16x8 qf[4][2];
#pragma unroll
    for (int qt = 0; qt < 4; qt++) {
        qf[qt][0] = load8(qb + ((qrow0 + qt * 16 + l16) << 6) + quad * 8);
        qf[qt][1] = load8(qb + ((qrow0 + qt * 16 + l16) << 6) + 32 + quad * 8);
    }

    bf16x8 ones;
#pragma unroll
    for (int e = 0; e < 8; e++) ones[e] = tobf(1.0f);

    f32x4 zero = {0.f, 0.f, 0.f, 0.f};
    f32x4 o_acc[4][4];
    f32x4 o_l[4];
#pragma unroll
    for (int qt = 0; qt < 4; qt++) {
        o_l[qt] = zero;
#pragma unroll
        for (int dj = 0; dj < 4; dj++) o_acc[qt][dj] = zero;
    }

    auto subchunk = [&](int kv0, bf16x8 (&kcur)[2][2], bf16x8 (&knxt)[2][2], bool pref) {
        // V loads for THIS subchunk: issued early, used after S^T+softmax (~400 cyc)
        bf16x8 vf[4];
#pragma unroll
        for (int dj = 0; dj < 4; dj++)
            vf[dj] = load8(vb + ((size_t)(dj * 16 + l16) << 11) + kv0 + quad * 8);
        // K prefetch for NEXT subchunk: covered by this subchunk's full compute
        if (pref) {
#pragma unroll
            for (int t = 0; t < 2; t++) {
                knxt[t][0] = load8(kb + ((kv0 + 32 + t * 16 + l16) << 6) + quad * 8);
                knxt[t][1] = load8(kb + ((kv0 + 32 + t * 16 + l16) << 6) + 32 + quad * 8);
            }
        }
        // S^T = K·Q^T; p = exp2(s); pack 4 consecutive keys per lane -> P
#pragma unroll
        for (int t = 0; t < 2; t++) {
#pragma unroll
            for (int qt = 0; qt < 4; qt++) {
                f32x4 st = __builtin_amdgcn_mfma_f32_16x16x32_bf16(kcur[t][0], qf[qt][0], zero, 0, 0, 0);
                st       = __builtin_amdgcn_mfma_f32_16x16x32_bf16(kcur[t][1], qf[qt][1], st, 0, 0, 0);
                const unsigned u0 = (unsigned)__bfloat16_as_ushort(__float2bfloat16(EXP2F(st[0])));
                const unsigned u1 = (unsigned)__bfloat16_as_ushort(__float2bfloat16(EXP2F(st[1])));
                const unsigned u2 = (unsigned)__bfloat16_as_ushort(__float2bfloat16(EXP2F(st[2])));
                const unsigned u3 = (unsigned)__bfloat16_as_ushort(__float2bfloat16(EXP2F(st[3])));
                uint2 w;
                w.x = (u1 << 16) | u0;
                w.y = (u3 << 16) | u2;
                *reinterpret_cast<uint2*>(&pw[(qt * 16 + l16) * 40 + t * 16 + quad * 4]) = w;
            }
        }
        // O += P·V; l += P·1 (ones-MFMA: row sums land in C-layout lanes directly)
#pragma unroll
        for (int qt = 0; qt < 4; qt++) {
            const bf16x8 pa = load8(&pw[(qt * 16 + l16) * 40 + quad * 8]);
            o_l[qt] = __builtin_amdgcn_mfma_f32_16x16x32_bf16(pa, ones, o_l[qt], 0, 0, 0);
#pragma unroll
            for (int dj = 0; dj < 4; dj++)
                o_acc[qt][dj] = __builtin_amdgcn_mfma_f32_16x16x32_bf16(pa, vf[dj], o_acc[qt][dj], 0, 0, 0);
        }
    };

    bf16x8 kA[2][2], kB[2][2];
#pragma unroll
    for (int t = 0; t < 2; t++) {    // prologue: K for keys 0..31
        kA[t][0] = load8(kb + ((t * 16 + l16) << 6) + quad * 8);
        kA[t][1] = load8(kb + ((t * 16 + l16) << 6) + 32 + quad * 8);
    }

    for (int kv0 = 0; kv0 < S_LEN; kv0 += 64) {
        subchunk(kv0,      kA, kB, true);
        subchunk(kv0 + 32, kB, kA, kv0 + 64 < S_LEN);
    }

    // epilogue: inv-l is already per-lane correct (o_l[qt][r] = l of qrow quad*4+r)
    const int b_ = bh >> 4, h_ = bh & 15;
#pragma unroll
    for (int qt = 0; qt < 4; qt++) {
#pragma unroll
        for (int r = 0; r < 4; r++) {
            const float inv = 1.f / o_l[qt][r];
            const size_t ro = ((size_t)b_ * S_LEN + (qrow0 + qt * 16 + quad * 4 + r)) * E_DIM + h_ * D_DIM;
#pragma unroll
            for (int dj = 0; dj < 4; dj++)
                Op[ro + dj * 16 + l16] = __float2bfloat16(o_acc[qt][dj][r] * inv);
        }
    }
}

// ---------------------------------------------------------------------------
extern "C" void kernel_launch(void* const* d_in, const int* in_sizes, int n_in,
                              void* d_out, int out_size, void* d_ws, size_t ws_size,
                              hipStream_t stream)
{
    const float* Qf  = (const float*)d_in[0];
    const float* Kf  = (const float*)d_in[1];
    const float* Vf  = (const float*)d_in[2];
    const float* Wqf = (const float*)d_in[3];
    const float* bqf = (const float*)d_in[4];
    const float* Wkf = (const float*)d_in[5];
    const float* bkf = (const float*)d_in[6];
    const float* Wvf = (const float*)d_in[7];
    const float* bvf = (const float*)d_in[8];
    const float* Wof = (const float*)d_in[9];
    const float* bof = (const float*)d_in[10];

    const size_t n_act = (size_t)M_ROWS * E_DIM;   // 8,388,608
    const size_t n_w   = (size_t)E_DIM * E_DIM;    // 1,048,576

    // Workspace (bf16 elems): 4 weights (8 MB) + Qt/Kt/Vt (48 MB) + X (16 MB) = 72 MB
    __hip_bfloat16* Wqb = (__hip_bfloat16*)d_ws;
    __hip_bfloat16* Wkb = Wqb + n_w;
    __hip_bfloat16* Wvb = Wkb + n_w;
    __hip_bfloat16* Wob = Wvb + n_w;
    __hip_bfloat16* Qt  = Wob + n_w;
    __hip_bfloat16* Kt  = Qt + n_act;
    __hip_bfloat16* Vt  = Kt + n_act;
    __hip_bfloat16* X   = Vt + n_act;

    const dim3 blk(256);
    const int cg_w = (int)(n_w / 8 / 256);   // 512 blocks per weight cvt

    cvt_f32_bf16<<<cg_w, blk, 0, stream>>>(Wqf, Wqb, (int)(n_w / 8));
    cvt_f32_bf16<<<cg_w, blk, 0, stream>>>(Wkf, Wkb, (int)(n_w / 8));
    cvt_f32_bf16<<<cg_w, blk, 0, stream>>>(Wvf, Wvb, (int)(n_w / 8));
    cvt_f32_bf16<<<cg_w, blk, 0, stream>>>(Wof, Wob, (int)(n_w / 8));

    QkvArgs qa;
    qa.d[0] = { Qf, Wqb, bqf, Qt, QK_SCALE, 0 };
    qa.d[1] = { Kf, Wkb, bkf, Kt, 1.0f,     0 };
    qa.d[2] = { Vf, Wvb, bvf, Vt, 1.0f,     1 };
    gemm_qkv<<<dim3(1536), blk, 0, stream>>>(qa);

    attn<<<dim3(512), blk, 0, stream>>>(Qt, Kt, Vt, X);

    gemm_o<<<dim3(512), blk, 0, stream>>>(X, Wob, bof, (float*)d_out);
}

// Round 7
// 439.291 us; speedup vs baseline: 1.0386x; 1.0386x over previous
//
#include <hip/hip_runtime.h>
#include <hip/hip_bf16.h>

// Problem constants
#define B_SZ   4
#define S_LEN  2048
#define E_DIM  1024
#define H_NUM  16
#define D_DIM  64
#define M_ROWS (B_SZ * S_LEN)            // 8192
#define QK_SCALE 0.1803368801111204f     // (1/sqrt(64)) * log2(e): softmax in exp2 domain

typedef __attribute__((ext_vector_type(8))) __bf16 bf16x8;
typedef __attribute__((ext_vector_type(4))) float  f32x4;

__device__ __forceinline__ bf16x8 load8(const __hip_bfloat16* p) {
    return __builtin_bit_cast(bf16x8, *reinterpret_cast<const uint4*>(p));
}
__device__ __forceinline__ __bf16 tobf(float x) {
    return __builtin_bit_cast(__bf16, __float2bfloat16(x));
}

#if defined(__has_builtin)
#if __has_builtin(__builtin_amdgcn_exp2f)
#define EXP2F(x) __builtin_amdgcn_exp2f(x)
#endif
#if __has_builtin(__builtin_amdgcn_global_load_lds)
#define HAVE_GLL 1
#endif
#endif
#ifndef EXP2F
#define EXP2F(x) exp2f(x)
#endif

// 16B-per-lane global->LDS stage. lbase wave-uniform; lane i lands at lbase+16i.
__device__ __forceinline__ void stage16g(const void* g, void* lbase, int lane) {
#ifdef HAVE_GLL
    __builtin_amdgcn_global_load_lds((const __attribute__((address_space(1))) unsigned int*)g,
                                     (__attribute__((address_space(3))) unsigned int*)lbase,
                                     16, 0, 0);
#else
    reinterpret_cast<uint4*>(lbase)[lane] = *reinterpret_cast<const uint4*>(g);
#endif
}

// ---------------------------------------------------------------------------
// f32 -> bf16 convert (weights), 8 elements/thread.
// ---------------------------------------------------------------------------
__global__ __launch_bounds__(256) void cvt_f32_bf16(const float* __restrict__ s,
                                                    __hip_bfloat16* __restrict__ d,
                                                    int n8)
{
    const int i = blockIdx.x * 256 + threadIdx.x;
    if (i >= n8) return;
    const float4 a = reinterpret_cast<const float4*>(s)[i * 2];
    const float4 b = reinterpret_cast<const float4*>(s)[i * 2 + 1];
    __hip_bfloat16 o[8];
    o[0] = __float2bfloat16(a.x); o[1] = __float2bfloat16(a.y);
    o[2] = __float2bfloat16(a.z); o[3] = __float2bfloat16(a.w);
    o[4] = __float2bfloat16(b.x); o[5] = __float2bfloat16(b.y);
    o[6] = __float2bfloat16(b.z); o[7] = __float2bfloat16(b.w);
    reinterpret_cast<uint4*>(d)[i] = *reinterpret_cast<uint4*>(o);
}

// ---------------------------------------------------------------------------
// Fused QKV projection GEMM: out = A(f32) @ W(bf16)^T + bias, 128x128 tile,
// BK=32, dbuf global_load_lds, 1 barrier/iter.
// XCD-affinity mapping: bm = idx&63, bn = idx>>6 -> the 8 blocks sharing one
// A-row-block have idx == bm (mod 8) -> same XCD (round-robin dispatch) ->
// A fetched once chip-wide instead of once per XCD.
// ---------------------------------------------------------------------------
struct QkvDesc { const float* A; const __hip_bfloat16* W; const float* bias;
                 __hip_bfloat16* out; float scale; int headsT; };
struct QkvArgs { QkvDesc d[3]; };

__global__ __launch_bounds__(256) void gemm_qkv(QkvArgs args)
{
    __shared__ float          AlsF[2][128 * 32];  // 2 x 16 KB
    __shared__ __hip_bfloat16 Bls [2][128 * 32];  // 2 x  8 KB

    const int proj = blockIdx.x >> 9;
    const int bidx = blockIdx.x & 511;
    const QkvDesc g = args.d[proj];

    const int wave = threadIdx.x >> 6, lane = threadIdx.x & 63;
    const int quad = lane >> 4, l16 = lane & 15;
    const int bm = bidx & 63, bn = bidx >> 6;     // XCD-affinity: same bm -> same XCD
    const int row0 = bm * 128, col0 = bn * 128;
    const int wm = (wave & 1) * 64, wn = (wave >> 1) * 64;

    // A staging source (f32): lane i -> row i>>3 (8-row seg), granule (i&7)^(row&7)
    const int arow = lane >> 3;
    const int agrn = (lane & 7) ^ (arow & 7);
    const float* gA = g.A + (size_t)(row0 + wave * 32 + arow) * E_DIM + agrn * 4;
    // B staging source (bf16): lane i -> row i>>2, granule (i&3)^(row&3)
    const int brow = lane >> 2;
    const int bgrn = (lane & 3) ^ (brow & 3);
    const __hip_bfloat16* gB = g.W + (size_t)(col0 + wave * 32 + brow) * E_DIM + bgrn * 8;

    f32x4 zero = {0.f, 0.f, 0.f, 0.f};
    f32x4 acc[4][4];
#pragma unroll
    for (int i = 0; i < 4; i++)
#pragma unroll
        for (int j = 0; j < 4; j++) acc[i][j] = zero;

    auto stage = [&](int buf, int kk) {
#pragma unroll
        for (int seg = 0; seg < 4; seg++)
            stage16g(gA + kk + (size_t)seg * 8 * E_DIM,
                     &AlsF[buf][(wave * 32 + seg * 8) * 32], lane);
#pragma unroll
        for (int seg = 0; seg < 2; seg++)
            stage16g(gB + kk + (size_t)seg * 16 * E_DIM,
                     &Bls[buf][(wave * 32 + seg * 16) * 32], lane);
    };

    stage(0, 0);
    __syncthreads();
    for (int it = 0; it < 32; ++it) {
        const int cb = it & 1;
        if (it < 31) stage(cb ^ 1, (it + 1) * 32);   // async prefetch during compute

        bf16x8 a[4], b[4];
#pragma unroll
        for (int i = 0; i < 4; i++) {
            const int row = wm + i * 16 + l16;
            const float* base = &AlsF[cb][row * 32];
            const f32x4 lo = *reinterpret_cast<const f32x4*>(base + ((2 * quad)     ^ (l16 & 7)) * 4);
            const f32x4 hi = *reinterpret_cast<const f32x4*>(base + ((2 * quad + 1) ^ (l16 & 7)) * 4);
            bf16x8 av;
#pragma unroll
            for (int e = 0; e < 4; e++) { av[e] = tobf(lo[e]); av[4 + e] = tobf(hi[e]); }
            a[i] = av;
        }
#pragma unroll
        for (int j = 0; j < 4; j++) {
            const int row = wn + j * 16 + l16;
            b[j] = load8(&Bls[cb][row * 32 + ((quad ^ (l16 & 3)) * 8)]);
        }
#pragma unroll
        for (int i = 0; i < 4; i++)
#pragma unroll
            for (int j = 0; j < 4; j++)
                acc[i][j] = __builtin_amdgcn_mfma_f32_16x16x32_bf16(a[i], b[j], acc[i][j], 0, 0, 0);
        __syncthreads();
    }

#pragma unroll
    for (int j = 0; j < 4; j++) {
        const int col = col0 + wn + j * 16 + l16;
        const float bv = g.bias[col];
        const int h_ = col >> 6, d_ = col & 63;
#pragma unroll
        for (int i = 0; i < 4; i++) {
            const int row = row0 + wm + i * 16 + quad * 4;
#pragma unroll
            for (int r = 0; r < 4; r++) {
                const float v = (acc[i][j][r] + bv) * g.scale;
                const int rr = row + r;
                const int b_ = rr >> 11, s_ = rr & 2047;
                if (!g.headsT)
                    g.out[(((size_t)(b_ * H_NUM + h_)) << 17) + (s_ << 6) + d_] = __float2bfloat16(v);
                else
                    g.out[(((size_t)(b_ * H_NUM + h_)) << 17) + (d_ << 11) + s_] = __float2bfloat16(v);
            }
        }
    }
}

// ---------------------------------------------------------------------------
// Output projection GEMM: C(f32) = A(bf16) @ W(bf16)^T + bias. Dbuf single-
// barrier, XOR-swizzled staging, XCD-affinity mapping.
// ---------------------------------------------------------------------------
__global__ __launch_bounds__(256) void gemm_o(const __hip_bfloat16* __restrict__ A,
                                              const __hip_bfloat16* __restrict__ W,
                                              const float* __restrict__ bias,
                                              float* __restrict__ C)
{
    __shared__ __hip_bfloat16 Als[2][128 * 32];
    __shared__ __hip_bfloat16 Bls[2][128 * 32];

    const int wave = threadIdx.x >> 6, lane = threadIdx.x & 63;
    const int quad = lane >> 4, l16 = lane & 15;
    const int bm = blockIdx.x & 63, bn = blockIdx.x >> 6;   // XCD-affinity
    const int row0 = bm * 128, col0 = bn * 128;
    const int wm = (wave & 1) * 64, wn = (wave >> 1) * 64;

    const int srow = lane >> 2;
    const int sgrn = (lane & 3) ^ (srow & 3);
    const __hip_bfloat16* gA = A + (size_t)(row0 + wave * 32 + srow) * E_DIM + sgrn * 8;
    const __hip_bfloat16* gB = W + (size_t)(col0 + wave * 32 + srow) * E_DIM + sgrn * 8;

    f32x4 zero = {0.f, 0.f, 0.f, 0.f};
    f32x4 acc[4][4];
#pragma unroll
    for (int i = 0; i < 4; i++)
#pragma unroll
        for (int j = 0; j < 4; j++) acc[i][j] = zero;

    auto stage = [&](int buf, int kk) {
#pragma unroll
        for (int seg = 0; seg < 2; seg++) {
            stage16g(gA + kk + (size_t)seg * 16 * E_DIM,
                     &Als[buf][(wave * 32 + seg * 16) * 32], lane);
            stage16g(gB + kk + (size_t)seg * 16 * E_DIM,
                     &Bls[buf][(wave * 32 + seg * 16) * 32], lane);
        }
    };

    stage(0, 0);
    __syncthreads();
    for (int it = 0; it < 32; ++it) {
        const int cb = it & 1;
        if (it < 31) stage(cb ^ 1, (it + 1) * 32);

        bf16x8 a[4], b[4];
#pragma unroll
        for (int i = 0; i < 4; i++)
            a[i] = load8(&Als[cb][(wm + i * 16 + l16) * 32 + ((quad ^ (l16 & 3)) * 8)]);
#pragma unroll
        for (int j = 0; j < 4; j++)
            b[j] = load8(&Bls[cb][(wn + j * 16 + l16) * 32 + ((quad ^ (l16 & 3)) * 8)]);
#pragma unroll
        for (int i = 0; i < 4; i++)
#pragma unroll
            for (int j = 0; j < 4; j++)
                acc[i][j] = __builtin_amdgcn_mfma_f32_16x16x32_bf16(a[i], b[j], acc[i][j], 0, 0, 0);
        __syncthreads();
    }

#pragma unroll
    for (int j = 0; j < 4; j++) {
        const int col = col0 + wn + j * 16 + l16;
        const float bv = bias[col];
#pragma unroll
        for (int i = 0; i < 4; i++) {
            const int row = row0 + wm + i * 16 + quad * 4;
#pragma unroll
            for (int r = 0; r < 4; r++)
                C[(size_t)(row + r) * E_DIM + col] = acc[i][j][r] + bv;
        }
    }
}

// ---------------------------------------------------------------------------
// Flash attention (r5-proven skeleton): barrier-free, 64 q-rows/wave, S^T
// trick, no-max exp2 softmax. Upgrades: V loads issued before S^T compute;
// l accumulated via ones-MFMA (row-sums land directly in C-layout lanes).
// Qt,Kt: [bh][s][d] bf16 (Qt prescaled by QK_SCALE). Vt: [bh][d][s] bf16.
// ---------------------------------------------------------------------------
__global__ __launch_bounds__(256) void attn(const __hip_bfloat16* __restrict__ Qt,
                                            const __hip_bfloat16* __restrict__ Kt,
                                            const __hip_bfloat16* __restrict__ Vt,
                                            __hip_bfloat16* __restrict__ Op)
{
    __shared__ __hip_bfloat16 Pls[4][64][40];   // per-wave [qrow][key32 + pad], 20 KB

    const int qchunk = blockIdx.x & 7;
    const int bh     = blockIdx.x >> 3;
    const int wave = threadIdx.x >> 6, lane = threadIdx.x & 63;
    const int quad = lane >> 4, l16 = lane & 15;
    const int qrow0 = qchunk * 256 + wave * 64;

    const __hip_bfloat16* qb = Qt + ((size_t)bh << 17);
    const __hip_bfloat16* kb = Kt + ((size_t)bh << 17);
    const __hip_bfloat16* vb = Vt + ((size_t)bh << 17);
    __hip_bfloat16* pw = &Pls[wave][0][0];

    bf16x8 qf[4][2];
#pragma unroll
    for (int qt = 0; qt < 4; qt++) {
        qf[qt][0] = load8(qb + ((qrow0 + qt * 16 + l16) << 6) + quad * 8);
        qf[qt][1] = load8(qb + ((qrow0 + qt * 16 + l16) << 6) + 32 + quad * 8);
    }

    bf16x8 ones;
#pragma unroll
    for (int e = 0; e < 8; e++) ones[e] = tobf(1.0f);

    f32x4 zero = {0.f, 0.f, 0.f, 0.f};
    f32x4 o_acc[4][4];
    f32x4 o_l[4];
#pragma unroll
    for (int qt = 0; qt < 4; qt++) {
        o_l[qt] = zero;
#pragma unroll
        for (int dj = 0; dj < 4; dj++) o_acc[qt][dj] = zero;
    }

    for (int kv0 = 0; kv0 < S_LEN; kv0 += 32) {
        // V for this chunk: issued first, consumed ~400 cyc later (after S^T+softmax)
        bf16x8 vf[4];
#pragma unroll
        for (int dj = 0; dj < 4; dj++)
            vf[dj] = load8(vb + ((size_t)(dj * 16 + l16) << 11) + kv0 + quad * 8);
        // K frags for both 16-key tiles
        bf16x8 kf[2][2];
#pragma unroll
        for (int t = 0; t < 2; t++) {
            kf[t][0] = load8(kb + ((kv0 + t * 16 + l16) << 6) + quad * 8);
            kf[t][1] = load8(kb + ((kv0 + t * 16 + l16) << 6) + 32 + quad * 8);
        }

        // S^T = K·Q^T; p = exp2(s); pack 4 consecutive keys per lane -> P
#pragma unroll
        for (int t = 0; t < 2; t++) {
#pragma unroll
            for (int qt = 0; qt < 4; qt++) {
                f32x4 st = __builtin_amdgcn_mfma_f32_16x16x32_bf16(kf[t][0], qf[qt][0], zero, 0, 0, 0);
                st       = __builtin_amdgcn_mfma_f32_16x16x32_bf16(kf[t][1], qf[qt][1], st, 0, 0, 0);
                const unsigned u0 = (unsigned)__bfloat16_as_ushort(__float2bfloat16(EXP2F(st[0])));
                const unsigned u1 = (unsigned)__bfloat16_as_ushort(__float2bfloat16(EXP2F(st[1])));
                const unsigned u2 = (unsigned)__bfloat16_as_ushort(__float2bfloat16(EXP2F(st[2])));
                const unsigned u3 = (unsigned)__bfloat16_as_ushort(__float2bfloat16(EXP2F(st[3])));
                uint2 w;
                w.x = (u1 << 16) | u0;
                w.y = (u3 << 16) | u2;
                *reinterpret_cast<uint2*>(&pw[(qt * 16 + l16) * 40 + t * 16 + quad * 4]) = w;
            }
        }

        // O += P·V ; l += P·1 (ones-MFMA)
#pragma unroll
        for (int qt = 0; qt < 4; qt++) {
            const bf16x8 pa = load8(&pw[(qt * 16 + l16) * 40 + quad * 8]);
            o_l[qt] = __builtin_amdgcn_mfma_f32_16x16x32_bf16(pa, ones, o_l[qt], 0, 0, 0);
#pragma unroll
            for (int dj = 0; dj < 4; dj++)
                o_acc[qt][dj] = __builtin_amdgcn_mfma_f32_16x16x32_bf16(pa, vf[dj], o_acc[qt][dj], 0, 0, 0);
        }
    }

    // epilogue: o_l[qt][r] is exactly l of qrow quad*4+r (uniform across l16)
    const int b_ = bh >> 4, h_ = bh & 15;
#pragma unroll
    for (int qt = 0; qt < 4; qt++) {
#pragma unroll
        for (int r = 0; r < 4; r++) {
            const float inv = 1.f / o_l[qt][r];
            const size_t ro = ((size_t)b_ * S_LEN + (qrow0 + qt * 16 + quad * 4 + r)) * E_DIM + h_ * D_DIM;
#pragma unroll
            for (int dj = 0; dj < 4; dj++)
                Op[ro + dj * 16 + l16] = __float2bfloat16(o_acc[qt][dj][r] * inv);
        }
    }
}

// ---------------------------------------------------------------------------
extern "C" void kernel_launch(void* const* d_in, const int* in_sizes, int n_in,
                              void* d_out, int out_size, void* d_ws, size_t ws_size,
                              hipStream_t stream)
{
    const float* Qf  = (const float*)d_in[0];
    const float* Kf  = (const float*)d_in[1];
    const float* Vf  = (const float*)d_in[2];
    const float* Wqf = (const float*)d_in[3];
    const float* bqf = (const float*)d_in[4];
    const float* Wkf = (const float*)d_in[5];
    const float* bkf = (const float*)d_in[6];
    const float* Wvf = (const float*)d_in[7];
    const float* bvf = (const float*)d_in[8];
    const float* Wof = (const float*)d_in[9];
    const float* bof = (const float*)d_in[10];

    const size_t n_act = (size_t)M_ROWS * E_DIM;   // 8,388,608
    const size_t n_w   = (size_t)E_DIM * E_DIM;    // 1,048,576

    // Workspace (bf16 elems): 4 weights (8 MB) + Qt/Kt/Vt (48 MB) + X (16 MB) = 72 MB
    __hip_bfloat16* Wqb = (__hip_bfloat16*)d_ws;
    __hip_bfloat16* Wkb = Wqb + n_w;
    __hip_bfloat16* Wvb = Wkb + n_w;
    __hip_bfloat16* Wob = Wvb + n_w;
    __hip_bfloat16* Qt  = Wob + n_w;
    __hip_bfloat16* Kt  = Qt + n_act;
    __hip_bfloat16* Vt  = Kt + n_act;
    __hip_bfloat16* X   = Vt + n_act;

    const dim3 blk(256);
    const int cg_w = (int)(n_w / 8 / 256);   // 512 blocks per weight cvt

    cvt_f32_bf16<<<cg_w, blk, 0, stream>>>(Wqf, Wqb, (int)(n_w / 8));
    cvt_f32_bf16<<<cg_w, blk, 0, stream>>>(Wkf, Wkb, (int)(n_w / 8));
    cvt_f32_bf16<<<cg_w, blk, 0, stream>>>(Wvf, Wvb, (int)(n_w / 8));
    cvt_f32_bf16<<<cg_w, blk, 0, stream>>>(Wof, Wob, (int)(n_w / 8));

    QkvArgs qa;
    qa.d[0] = { Qf, Wqb, bqf, Qt, QK_SCALE, 0 };
    qa.d[1] = { Kf, Wkb, bkf, Kt, 1.0f,     0 };
    qa.d[2] = { Vf, Wvb, bvf, Vt, 1.0f,     1 };
    gemm_qkv<<<dim3(1536), blk, 0, stream>>>(qa);

    attn<<<dim3(512), blk, 0, stream>>>(Qt, Kt, Vt, X);

    gemm_o<<<dim3(512), blk, 0, stream>>>(X, Wob, bof, (float*)d_out);
}